// Round 8
// baseline (77.384 us; speedup 1.0000x reference)
//
#include <hip/hip_runtime.h>

// Problem constants (fixed by the reference)
#define BATCH 128
#define C 64
#define L 4096
#define K 31

#define NT 256
#define NWAVE 4
#define CPW (C / NWAVE)      // 16 channels per wave
#define RW 8                 // outputs per lane
#define TILE 512             // outputs per block (all 4 waves share this tile)

typedef float floatx4 __attribute__((ext_vector_type(4)));

__device__ __forceinline__ floatx4 ld4(const float* p) {
    return *reinterpret_cast<const floatx4*>(p);
}

// out[b,o,l] = S[b,l] for all o, S[b,l] = sum_i sum_k w[i,k]*x[b,i,l+15-k]
// (x zero outside [0,L); kernel is broadcast over o).
//
// Fused single pass. Per block: 512-output tile; wave wv accumulates the
// partial over channels [wv*16, wv*16+16) using the amplification-free
// shuffle-window (each lane loads exactly its own 8 floats/channel, window
// assembled by cross-lane shfl; lanes 0,1,62,63 patch via halo loads).
// One LDS psum[4][512] + one barrier, register reduce, then each wave
// broadcast-stores the tile to its 16 output channels (nt, coalesced).
__global__ __launch_bounds__(NT, 4)
void revconv_fused(const float* __restrict__ x,
                   const float* __restrict__ w,
                   float* __restrict__ out) {
    __shared__ __align__(16) float psum[NWAVE][TILE];

    const int tid  = threadIdx.x;
    const int wv   = tid >> 6;
    const int lane = tid & 63;
    const int tile = blockIdx.x;          // 0..7
    const int b    = blockIdx.y;          // 0..127
    const int W0   = tile * TILE;         // block's first output (wave-uniform)
    const int l0   = W0 + lane * RW;      // lane's first output
    const int i0   = wv * CPW;
    const float* xb = x + (long)b * C * L;

    const bool lo   = (lane < 2);
    const bool ln0  = (lane == 0);
    const bool hi   = (lane >= 62);
    const bool ln63 = (lane == 63);
    const bool leftOK  = (W0 > 0);
    const bool rightOK = (W0 + TILE < L);

    float acc[RW];
#pragma unroll
    for (int r = 0; r < RW; ++r) acc[r] = 0.f;

    // prologue: own load for first channel
    floatx4 oa = ld4(xb + (long)i0 * L + l0);
    floatx4 obv = ld4(xb + (long)i0 * L + l0 + 4);

    for (int c = 0; c < CPW; ++c) {
        const int i = i0 + c;
        const float* xi = xb + (long)i * L;

        // halo loads (boundary lanes only; zeros at array edges)
        floatx4 hA0, hA1, hB0, hB1;
        hA0 = 0.f; hA1 = 0.f; hB0 = 0.f; hB1 = 0.f;
        if (lo && leftOK) {
            const float* hp = xi + l0 - 16;
            hA0 = ld4(hp); hA1 = ld4(hp + 4);
            if (ln0) { hB0 = ld4(hp + 8); hB1 = ld4(hp + 12); }
        }
        if (hi && rightOK) {
            const float* hp = xi + W0 + TILE;
            if (ln63) { hA0 = ld4(hp + 8); hA1 = ld4(hp + 12); hB0 = ld4(hp); hB1 = ld4(hp + 4); }
            else      { hA0 = ld4(hp);     hA1 = ld4(hp + 4); }
        }

        // prefetch next channel's own data (1-deep)
        floatx4 na = oa, nb = obv;
        if (c + 1 < CPW) {
            const float* np = xi + L + l0;
            na = ld4(np); nb = ld4(np + 4);
        }

        // assemble window win[j] = x[l0 - 16 + j], j = 0..39
        float own[RW] = {oa.x, oa.y, oa.z, oa.w, obv.x, obv.y, obv.z, obv.w};
        float win[40];
#pragma unroll
        for (int j = 0; j < RW; ++j) {
            win[j]      = __shfl_up(own[j], 2, 64);
            win[8 + j]  = __shfl_up(own[j], 1, 64);
            win[16 + j] = own[j];
            win[24 + j] = __shfl_down(own[j], 1, 64);
            win[32 + j] = __shfl_down(own[j], 2, 64);
        }
        if (lo) {
            win[0] = hA0.x; win[1] = hA0.y; win[2] = hA0.z; win[3] = hA0.w;
            win[4] = hA1.x; win[5] = hA1.y; win[6] = hA1.z; win[7] = hA1.w;
            if (ln0) {
                win[8]  = hB0.x; win[9]  = hB0.y; win[10] = hB0.z; win[11] = hB0.w;
                win[12] = hB1.x; win[13] = hB1.y; win[14] = hB1.z; win[15] = hB1.w;
            }
        }
        if (hi) {
            win[32] = hA0.x; win[33] = hA0.y; win[34] = hA0.z; win[35] = hA0.w;
            win[36] = hA1.x; win[37] = hA1.y; win[38] = hA1.z; win[39] = hA1.w;
            if (ln63) {
                win[24] = hB0.x; win[25] = hB0.y; win[26] = hB0.z; win[27] = hB0.w;
                win[28] = hB1.x; win[29] = hB1.y; win[30] = hB1.z; win[31] = hB1.w;
            }
        }

        const float* wp = w + i * K;   // wave-uniform -> scalar loads
#pragma unroll
        for (int k = 0; k < K; ++k) {
            const float wk = wp[k];
#pragma unroll
            for (int r = 0; r < RW; ++r)
                acc[r] += wk * win[r + 31 - k];
        }

        oa = na; obv = nb;
    }

    // stash partial, one barrier, register reduce across the 4 waves
    const int lt = lane * RW;
    {
        floatx4 a0, a1;
        a0.x = acc[0]; a0.y = acc[1]; a0.z = acc[2]; a0.w = acc[3];
        a1.x = acc[4]; a1.y = acc[5]; a1.z = acc[6]; a1.w = acc[7];
        *reinterpret_cast<floatx4*>(&psum[wv][lt])     = a0;
        *reinterpret_cast<floatx4*>(&psum[wv][lt + 4]) = a1;
    }
    __syncthreads();

    floatx4 v0 = ld4(&psum[0][lt]);
    floatx4 v1 = ld4(&psum[0][lt + 4]);
#pragma unroll
    for (int p = 1; p < NWAVE; ++p) {
        v0 += ld4(&psum[p][lt]);
        v1 += ld4(&psum[p][lt + 4]);
    }

    // broadcast-store the tile to this wave's 16 output channels
    float* ob = out + ((long)b * C + i0) * L + l0;
#pragma unroll
    for (int o = 0; o < CPW; ++o) {
        float* op = ob + (long)o * L;
        __builtin_nontemporal_store(v0, reinterpret_cast<floatx4*>(op));
        __builtin_nontemporal_store(v1, reinterpret_cast<floatx4*>(op + 4));
    }
}

extern "C" void kernel_launch(void* const* d_in, const int* in_sizes, int n_in,
                              void* d_out, int out_size, void* d_ws, size_t ws_size,
                              hipStream_t stream) {
    const float* x = (const float*)d_in[0];   // [B, C, L] fp32
    const float* w = (const float*)d_in[1];   // [C, C, K] fp32; o=0 slice used
    float* out = (float*)d_out;               // [B, C, L] fp32

    dim3 grid(L / TILE, BATCH);               // 8 x 128 = 1024 blocks
    revconv_fused<<<grid, NT, 0, stream>>>(x, w, out);
}

// Round 9
// 68.080 us; speedup vs baseline: 1.1367x; 1.1367x over previous
//
#include <hip/hip_runtime.h>

// Problem constants (fixed by the reference)
#define BATCH 128
#define C 64
#define L 4096
#define K 31

#define NT 256
#define CG 8                 // channel groups (blocks split over channels)
#define CPB (C / CG)         // 8 channels per block
#define RW 8                 // outputs per lane
#define WTILE 512            // outputs per wave (64 lanes * RW)
#define BTILE 2048           // outputs per block (4 waves)

typedef float floatx4 __attribute__((ext_vector_type(4)));

__device__ __forceinline__ floatx4 ld4(const float* p) {
    return *reinterpret_cast<const floatx4*>(p);
}

// ---- K1: Sp[cg][b][l] = sum_{i in cg} sum_k w[i,k] * x[b,i,l+15-k]
// Amplification-free shuffle-window (round-7 proven), now with CG=8 so the
// grid is 2048 blocks = 8 blocks/CU = 8 waves/SIMD (max TLP at VGPR<=64).
__global__ __launch_bounds__(NT, 4)
void computeS_kernel(const float* __restrict__ x,
                     const float* __restrict__ w,
                     float* __restrict__ Sp) {
    const int tid  = threadIdx.x;
    const int wv   = tid >> 6;
    const int lane = tid & 63;
    const int tile = blockIdx.x;          // 0..1
    const int b    = blockIdx.y;          // 0..127
    const int cg   = blockIdx.z;          // 0..7
    const int W0   = tile * BTILE + wv * WTILE;   // wave's first output
    const int l0   = W0 + lane * RW;              // lane's first output
    const int i0   = cg * CPB;
    const float* xb = x + (long)b * C * L;

    const bool lo   = (lane < 2);
    const bool ln0  = (lane == 0);
    const bool hi   = (lane >= 62);
    const bool ln63 = (lane == 63);
    const bool leftOK  = (W0 > 0);             // wave-uniform
    const bool rightOK = (W0 + WTILE < L);     // wave-uniform

    float acc[RW];
#pragma unroll
    for (int r = 0; r < RW; ++r) acc[r] = 0.f;

    // prologue: own load for first channel
    floatx4 oa = ld4(xb + (long)i0 * L + l0);
    floatx4 obv = ld4(xb + (long)i0 * L + l0 + 4);

    for (int c = 0; c < CPB; ++c) {
        const int i = i0 + c;
        const float* xi = xb + (long)i * L;

        // halo loads (boundary lanes only; zeros at array edges)
        floatx4 hA0, hA1, hB0, hB1;
        hA0 = 0.f; hA1 = 0.f; hB0 = 0.f; hB1 = 0.f;
        if (lo && leftOK) {
            const float* hp = xi + l0 - 16;
            hA0 = ld4(hp); hA1 = ld4(hp + 4);
            if (ln0) { hB0 = ld4(hp + 8); hB1 = ld4(hp + 12); }
        }
        if (hi && rightOK) {
            const float* hp = xi + W0 + WTILE;
            if (ln63) { hA0 = ld4(hp + 8); hA1 = ld4(hp + 12); hB0 = ld4(hp); hB1 = ld4(hp + 4); }
            else      { hA0 = ld4(hp);     hA1 = ld4(hp + 4); }
        }

        // prefetch next channel's own data (1-deep; TLP covers the rest)
        floatx4 na = oa, nb = obv;
        if (c + 1 < CPB) {
            const float* np = xi + L + l0;   // channel i+1
            na = ld4(np); nb = ld4(np + 4);
        }

        // assemble window win[j] = x[l0 - 16 + j], j = 0..39
        float own[RW] = {oa.x, oa.y, oa.z, oa.w, obv.x, obv.y, obv.z, obv.w};
        float win[40];
#pragma unroll
        for (int j = 0; j < RW; ++j) {
            win[j]      = __shfl_up(own[j], 2, 64);   // lanes<2 fixed below
            win[8 + j]  = __shfl_up(own[j], 1, 64);   // lane0 fixed below
            win[16 + j] = own[j];
            win[24 + j] = __shfl_down(own[j], 1, 64); // lane63 fixed below
            win[32 + j] = __shfl_down(own[j], 2, 64); // lanes>=62 fixed below
        }
        if (lo) {
            win[0] = hA0.x; win[1] = hA0.y; win[2] = hA0.z; win[3] = hA0.w;
            win[4] = hA1.x; win[5] = hA1.y; win[6] = hA1.z; win[7] = hA1.w;
            if (ln0) {
                win[8]  = hB0.x; win[9]  = hB0.y; win[10] = hB0.z; win[11] = hB0.w;
                win[12] = hB1.x; win[13] = hB1.y; win[14] = hB1.z; win[15] = hB1.w;
            }
        }
        if (hi) {
            win[32] = hA0.x; win[33] = hA0.y; win[34] = hA0.z; win[35] = hA0.w;
            win[36] = hA1.x; win[37] = hA1.y; win[38] = hA1.z; win[39] = hA1.w;
            if (ln63) {
                win[24] = hB0.x; win[25] = hB0.y; win[26] = hB0.z; win[27] = hB0.w;
                win[28] = hB1.x; win[29] = hB1.y; win[30] = hB1.z; win[31] = hB1.w;
            }
        }

        const float* wp = w + i * K;   // wave-uniform -> scalar loads
#pragma unroll
        for (int k = 0; k < K; ++k) {
            const float wk = wp[k];
#pragma unroll
            for (int r = 0; r < RW; ++r)
                acc[r] += wk * win[r + 31 - k];
        }

        oa = na; obv = nb;
    }

    floatx4 v0, v1;
    v0.x = acc[0]; v0.y = acc[1]; v0.z = acc[2]; v0.w = acc[3];
    v1.x = acc[4]; v1.y = acc[5]; v1.z = acc[6]; v1.w = acc[7];
    float* sp = Sp + ((long)cg * BATCH + b) * L + l0;
    *reinterpret_cast<floatx4*>(sp) = v0;
    *reinterpret_cast<floatx4*>(sp + 4) = v1;
}

// ---- K2: out[b,o,l] = sum_cg Sp[cg][b][l] — dense streaming broadcast.
__global__ __launch_bounds__(NT)
void broadcast_kernel(const float* __restrict__ Sp,
                      float* __restrict__ out) {
    const int lane = threadIdx.x & 63;
    const int og   = threadIdx.x >> 6;            // 0..3
    const int b    = blockIdx.y;
    const int l4   = blockIdx.x * 64 + lane;      // float4 column index
    const long sbase = (long)b * L + (long)l4 * 4;

    floatx4 v = *reinterpret_cast<const floatx4*>(Sp + sbase);
#pragma unroll
    for (int cg = 1; cg < CG; ++cg)
        v += *reinterpret_cast<const floatx4*>(Sp + (long)cg * BATCH * L + sbase);

    float* ob = out + ((long)b * C + og * 16) * L + (long)l4 * 4;
#pragma unroll
    for (int o = 0; o < 16; ++o)
        __builtin_nontemporal_store(v, reinterpret_cast<floatx4*>(ob + (long)o * L));
}

// ---- Fallback (proven round-3 fused kernel) if ws too small ----
#define FB_R 4
#define FB_TILE (NT * FB_R)
#define FB_WIN 36
__global__ __launch_bounds__(NT)
void fused_kernel(const float* __restrict__ x,
                  const float* __restrict__ w,
                  float* __restrict__ out) {
    const int tid = threadIdx.x;
    const int tile = blockIdx.x;
    const int b = blockIdx.y;
    const int l0 = tile * FB_TILE + tid * FB_R;
    float acc[FB_R] = {0.f, 0.f, 0.f, 0.f};
    const float* xb = x + (long)b * C * L;
    const bool interior = (l0 >= 16) && (l0 + 20 <= L);
    if (interior) {
        const float* xw = xb + (l0 - 16);
#pragma unroll 2
        for (int i = 0; i < C; ++i) {
            float win[FB_WIN];
            const floatx4* p = reinterpret_cast<const floatx4*>(xw + (long)i * L);
#pragma unroll
            for (int j = 0; j < FB_WIN / 4; ++j)
                reinterpret_cast<floatx4*>(win)[j] = p[j];
            const float* wp = w + i * K;
#pragma unroll
            for (int k = 0; k < K; ++k) {
                const float wk = wp[k];
#pragma unroll
                for (int r = 0; r < FB_R; ++r)
                    acc[r] += wk * win[r + 31 - k];
            }
        }
    } else {
        for (int i = 0; i < C; ++i) {
            const float* xi = xb + (long)i * L;
            float win[FB_WIN];
#pragma unroll
            for (int j = 0; j < FB_WIN; ++j) {
                const int g = l0 - 16 + j;
                win[j] = (g >= 0 && g < L) ? xi[g] : 0.f;
            }
            const float* wp = w + i * K;
#pragma unroll
            for (int k = 0; k < K; ++k) {
                const float wk = wp[k];
#pragma unroll
                for (int r = 0; r < FB_R; ++r)
                    acc[r] += wk * win[r + 31 - k];
            }
        }
    }
    float* op = out + (long)b * C * L + l0;
    floatx4 v; v.x = acc[0]; v.y = acc[1]; v.z = acc[2]; v.w = acc[3];
#pragma unroll
    for (int o = 0; o < C; ++o)
        __builtin_nontemporal_store(v, reinterpret_cast<floatx4*>(op + (long)o * L));
}

extern "C" void kernel_launch(void* const* d_in, const int* in_sizes, int n_in,
                              void* d_out, int out_size, void* d_ws, size_t ws_size,
                              hipStream_t stream) {
    const float* x = (const float*)d_in[0];   // [B, C, L] fp32
    const float* w = (const float*)d_in[1];   // [C, C, K] fp32; o=0 slice used
    float* out = (float*)d_out;               // [B, C, L] fp32

    const size_t sp_bytes = (size_t)CG * BATCH * L * sizeof(float);   // 16 MB
    if (ws_size >= sp_bytes) {
        float* Sp = (float*)d_ws;
        dim3 grid1(L / BTILE, BATCH, CG);         // 2 x 128 x 8 = 2048 blocks
        computeS_kernel<<<grid1, NT, 0, stream>>>(x, w, Sp);
        dim3 grid2(L / 256, BATCH);               // 2048 blocks
        broadcast_kernel<<<grid2, NT, 0, stream>>>(Sp, out);
    } else {
        dim3 grid(L / FB_TILE, BATCH);
        fused_kernel<<<grid, NT, 0, stream>>>(x, w, out);
    }
}